// Round 4
// baseline (121.127 us; speedup 1.0000x reference)
//
#include <hip/hip_runtime.h>
#include <hip/hip_bf16.h>

// ControlFieldModule (fp32 I/O), MFMA-bf16 GEMM, A-operand in registers.
//   fiber = H @ Wf + bf                         [32768, 32]
//   h     = gelu([H|fiber] @ W1 + b1)           [32768, 64]
//   delta = clip(softplus(h @ w2 + b2), 0, 1)   [32768]
//   field = EMA(delta, 0.9) clip [0,10]; gate = sigmoid(-field)
// One GEMM C[32768,96] = H @ [Wf | W1h + Wf@W1f] (bias folded).
// A (hidden) fragments: direct global->reg burst (32 dwordx4/lane), no LDS.
// B (96x512 bf16): LDS, 4 K-chunks. Scan: exact associative prefix scan.

#define NTOK  32768   // 8 * 4096
#define SEQ   4096
#define DM    512
#define NC    96      // 32 fiber + 64 control cols
#define TB    64      // tokens per block
#define LROW  136     // B LDS row stride in bf16 (272 B = 68 dw; 2-way bank alias = free)

typedef short bf16x8 __attribute__((ext_vector_type(8)));
typedef float f32x4  __attribute__((ext_vector_type(4)));

__device__ __forceinline__ unsigned short f2bf(float f) {
    __hip_bfloat16 h = __float2bfloat16(f);
    return *reinterpret_cast<unsigned short*>(&h);
}

// ---- kernel 1: Wt = [Wf | W1h + Wf@W1f]^T bf16 [96][512]; bc fp32 [96] ----
__global__ __launch_bounds__(256)
void prep_kernel(const float* __restrict__ wf,   // [512,32]
                 const float* __restrict__ bfb,  // [32]
                 const float* __restrict__ w1,   // [544,64]
                 const float* __restrict__ b1,   // [64]
                 unsigned short* __restrict__ Wt, // [96,512] bf16
                 float* __restrict__ bc)          // [96]
{
    int idx = blockIdx.x * 256 + threadIdx.x;     // 0 .. 96*512-1
    if (idx < NC * DM) {
        int n = idx >> 9, k = idx & 511;
        float v;
        if (n < 32) {
            v = wf[k * 32 + n];
        } else {
            int c = n - 32;
            v = w1[k * 64 + c];
            for (int f = 0; f < 32; ++f)
                v = fmaf(wf[k * 32 + f], w1[(512 + f) * 64 + c], v);
        }
        Wt[idx] = f2bf(v);
    }
    if (idx < NC) {
        float v;
        if (idx < 32) {
            v = bfb[idx];
        } else {
            int c = idx - 32;
            v = b1[c];
            for (int f = 0; f < 32; ++f)
                v = fmaf(bfb[f], w1[(512 + f) * 64 + c], v);
        }
        bc[idx] = v;
    }
}

// ---- kernel 2: MFMA GEMM, M=64/block, N=96, K=512; A in registers --------
// 256 threads = 4 waves; wave w owns tokens [tok0+16w, tok0+16w+16), 6 N-tiles.
__global__ __launch_bounds__(256, 2)
void fused_gemm_kernel(const float* __restrict__ hidden,        // [NTOK,512]
                       const unsigned short* __restrict__ Wt,   // [96,512] bf16
                       const float* __restrict__ bc,            // [96]
                       const float* __restrict__ w2,            // [64]
                       const float* __restrict__ b2,            // [1]
                       float* __restrict__ out_delta,           // [NTOK]
                       float* __restrict__ out_fiber)           // [NTOK,32]
{
    __shared__ unsigned short b_lds[NC * LROW];   // 26112 B

    const int tid  = threadIdx.x;
    const int wave = tid >> 6;
    const int lane = tid & 63;
    const int quad = lane >> 4;
    const int l15  = lane & 15;
    const int tok0 = blockIdx.x * TB;

    // ---- A: load my row's full K into bf16 fragments (frag j covers k=j*32+quad*8) ----
    const float* aptr = hidden + (size_t)(tok0 + wave * 16 + l15) * DM + quad * 8;
    bf16x8 afrag[16];
#pragma unroll
    for (int half = 0; half < 2; ++half) {
        float4 raw[16];
#pragma unroll
        for (int i = 0; i < 16; ++i)            // i = ks*2 + part
            raw[i] = *(const float4*)(aptr + half * 256 + (i >> 1) * 32 + (i & 1) * 4);
#pragma unroll
        for (int ks = 0; ks < 8; ++ks) {
            float4 lo = raw[ks * 2], hi = raw[ks * 2 + 1];
            bf16x8 f;
            f[0] = (short)f2bf(lo.x); f[1] = (short)f2bf(lo.y);
            f[2] = (short)f2bf(lo.z); f[3] = (short)f2bf(lo.w);
            f[4] = (short)f2bf(hi.x); f[5] = (short)f2bf(hi.y);
            f[6] = (short)f2bf(hi.z); f[7] = (short)f2bf(hi.w);
            afrag[half * 8 + ks] = f;
        }
    }

    f32x4 acc[6];
#pragma unroll
    for (int t = 0; t < 6; ++t) acc[t] = (f32x4){0.f, 0.f, 0.f, 0.f};

    for (int kc = 0; kc < 4; ++kc) {            // 4 chunks of K=128
        // stage B chunk: 96 rows x 128 k (1536 x 16B / 256 thr)
#pragma unroll
        for (int it = 0; it < 6; ++it) {
            int v   = it * 256 + tid;
            int row = v >> 4;
            int c8  = v & 15;
            *(bf16x8*)&b_lds[row * LROW + c8 * 8] =
                *(const bf16x8*)(Wt + row * DM + kc * 128 + c8 * 8);
        }
        __syncthreads();

#pragma unroll
        for (int ks = 0; ks < 4; ++ks) {
            bf16x8 af = afrag[kc * 4 + ks];
#pragma unroll
            for (int t = 0; t < 6; ++t) {
                bf16x8 bfv = *(const bf16x8*)&b_lds[(t * 16 + l15) * LROW + ks * 32 + quad * 8];
                acc[t] = __builtin_amdgcn_mfma_f32_16x16x32_bf16(af, bfv, acc[t], 0, 0, 0);
            }
        }
        __syncthreads();
    }

    // ---- epilogue: C/D layout col=lane&15, row=quad*4+reg ----
    const int mbase = tok0 + wave * 16 + quad * 4;

#pragma unroll
    for (int t = 0; t < 2; ++t) {               // fiber tiles
        int col = t * 16 + l15;
        float bias = bc[col];
#pragma unroll
        for (int r = 0; r < 4; ++r)
            out_fiber[(size_t)(mbase + r) * 32 + col] = acc[t][r] + bias;
    }

    float p0 = 0.f, p1 = 0.f, p2 = 0.f, p3 = 0.f;
#pragma unroll
    for (int t = 2; t < 6; ++t) {               // control tiles: gelu * w2
        int c = (t - 2) * 16 + l15;
        float bias = bc[32 + c];
        float w2v  = w2[c];
        float x, g;
        x = acc[t][0] + bias; g = 0.5f * x * (1.f + erff(x * 0.70710678118f)); p0 = fmaf(g, w2v, p0);
        x = acc[t][1] + bias; g = 0.5f * x * (1.f + erff(x * 0.70710678118f)); p1 = fmaf(g, w2v, p1);
        x = acc[t][2] + bias; g = 0.5f * x * (1.f + erff(x * 0.70710678118f)); p2 = fmaf(g, w2v, p2);
        x = acc[t][3] + bias; g = 0.5f * x * (1.f + erff(x * 0.70710678118f)); p3 = fmaf(g, w2v, p3);
    }
#pragma unroll
    for (int m = 1; m <= 8; m <<= 1) {          // reduce 16 lanes of this quad
        p0 += __shfl_xor(p0, m);
        p1 += __shfl_xor(p1, m);
        p2 += __shfl_xor(p2, m);
        p3 += __shfl_xor(p3, m);
    }
    if (l15 < 4) {
        float pv = (l15 == 0) ? p0 : (l15 == 1) ? p1 : (l15 == 2) ? p2 : p3;
        float s = pv + b2[0];
        float d = (s > 0.f) ? s + log1pf(expf(-s)) : log1pf(expf(s));
        d = fminf(fmaxf(d, 0.f), 1.f);
        out_delta[mbase + l15] = d;
    }
}

// ---- kernel 3: exact associative EMA scan + gate; 1 block per batch row ---
// 512 threads x 8 tokens. combine((a1,b1),(a2,b2)) = (a1*a2, a2*b1 + b2).
__global__ __launch_bounds__(512)
void scan_kernel(const float* __restrict__ delta,   // [8,4096]
                 const float* __restrict__ lam,     // scalar
                 float* __restrict__ out_gate,      // [NTOK]
                 float* __restrict__ out_field)     // [NTOK]
{
    __shared__ float sA[8], sB[8];
    const int b    = blockIdx.x;
    const int tid  = threadIdx.x;
    const int lane = tid & 63;
    const int wv   = tid >> 6;

    const float* dp = delta + (size_t)b * SEQ + tid * 8;
    float4 d0 = *(const float4*)dp;
    float4 d1 = *(const float4*)(dp + 4);
    float d[8] = {d0.x, d0.y, d0.z, d0.w, d1.x, d1.y, d1.z, d1.w};

    // segment result with zero init
    float x = 0.f;
#pragma unroll
    for (int j = 0; j < 8; ++j) x = fmaf(0.9f, x, 0.1f * d[j]);
    float A = 0.430467196f;   // 0.9^8
    float B = x;

    // inclusive scan across the 64-lane wave
#pragma unroll
    for (int m = 1; m <= 32; m <<= 1) {
        float Au = __shfl_up(A, m);
        float Bu = __shfl_up(B, m);
        if (lane >= m) { B = fmaf(A, Bu, B); A *= Au; }
    }
    if (lane == 63) { sA[wv] = A; sB[wv] = B; }
    __syncthreads();

    // carry from preceding waves
    float cA = 1.f, cB = 0.f;
    for (int i = 0; i < wv; ++i) { cB = fmaf(sA[i], cB, sB[i]); cA *= sA[i]; }

    // exclusive prefix for this thread = combine(carry, inclusive[lane-1])
    float Ap = __shfl_up(A, 1);
    float Bp = __shfl_up(B, 1);
    float f0 = (lane == 0) ? cB : fmaf(Ap, cB, Bp);

    const float lamv = lam[0];
    float xx = f0;
    float4 of0, of1, og0, og1;
    float* ofp = &of0.x;
    float* ogp = &og0.x;
#pragma unroll
    for (int j = 0; j < 8; ++j) {
        xx = fmaf(0.9f, xx, 0.1f * d[j]);
        float field = fminf(fmaxf(xx, 0.f), 10.f);
        float gate  = 1.f / (1.f + expf(lamv * field));
        if (j < 4) { (&of0.x)[j] = field; (&og0.x)[j] = gate; }
        else       { (&of1.x)[j - 4] = field; (&og1.x)[j - 4] = gate; }
    }
    (void)ofp; (void)ogp; (void)cA;
    size_t o = (size_t)b * SEQ + tid * 8;
    *(float4*)(out_field + o)     = of0;
    *(float4*)(out_field + o + 4) = of1;
    *(float4*)(out_gate  + o)     = og0;
    *(float4*)(out_gate  + o + 4) = og1;
}

// ---- launcher ----
extern "C" void kernel_launch(void* const* d_in, const int* in_sizes, int n_in,
                              void* d_out, int out_size, void* d_ws, size_t ws_size,
                              hipStream_t stream)
{
    const float* hidden = (const float*)d_in[0];
    const float* wf     = (const float*)d_in[1];
    const float* bfb    = (const float*)d_in[2];
    const float* w1     = (const float*)d_in[3];
    const float* b1     = (const float*)d_in[4];
    const float* w2     = (const float*)d_in[5];
    const float* b2     = (const float*)d_in[6];
    const float* lam    = (const float*)d_in[7];
    float* out = (float*)d_out;
    // out layout: gate[32768] | field[32768] | delta[32768] | fiber[32768*32]
    float* out_gate  = out;
    float* out_field = out + NTOK;
    float* out_delta = out + 2 * NTOK;
    float* out_fiber = out + 3 * NTOK;

    unsigned short* Wt = (unsigned short*)d_ws;                 // 96*512*2 B
    float* bc          = (float*)((char*)d_ws + NC * DM * 2);   // 384 B

    hipLaunchKernelGGL(prep_kernel, dim3((NC * DM + 255) / 256), dim3(256), 0, stream,
                       wf, bfb, w1, b1, Wt, bc);
    hipLaunchKernelGGL(fused_gemm_kernel, dim3(NTOK / TB), dim3(256), 0, stream,
                       hidden, Wt, bc, w2, b2, out_delta, out_fiber);
    hipLaunchKernelGGL(scan_kernel, dim3(8), dim3(512), 0, stream,
                       out_delta, lam, out_gate, out_field);
}

// Round 5
// 118.238 us; speedup vs baseline: 1.0244x; 1.0244x over previous
//
#include <hip/hip_runtime.h>
#include <hip/hip_bf16.h>

// ControlFieldModule (fp32 I/O), MFMA-bf16 GEMM with in-block split-K.
//   fiber = H @ Wf + bf; h = gelu([H|fiber]@W1+b1); delta = clip(softplus(h@w2+b2),0,1)
//   field = EMA(delta,0.9) clip[0,10]; gate = sigmoid(-field)
// One GEMM C[32768,96] = H @ [Wf | W1h + Wf@W1f] (bias folded into bc).
// 512 thr/block = 8 waves: 4 M-waves x 2 K-halves (K=256 each, A in registers).
// B (96x512 bf16) staged in LDS per 128-chunk for both halves at once.
// EMA: exact associative prefix scan.

#define NTOK  32768   // 8 * 4096
#define SEQ   4096
#define DM    512
#define NC    96      // 32 fiber + 64 control cols
#define TB    64      // tokens per block
#define LROW  136     // B LDS row stride in bf16 (272 B; balanced bank groups)

typedef short bf16x8 __attribute__((ext_vector_type(8)));
typedef float f32x4  __attribute__((ext_vector_type(4)));

__device__ __forceinline__ unsigned short f2bf(float f) {
    __hip_bfloat16 h = __float2bfloat16(f);
    return *reinterpret_cast<unsigned short*>(&h);
}

// ---- kernel 1: Wt = [Wf | W1h + Wf@W1f]^T bf16 [96][512]; bc fp32 [96] ----
__global__ __launch_bounds__(256)
void prep_kernel(const float* __restrict__ wf,   // [512,32]
                 const float* __restrict__ bfb,  // [32]
                 const float* __restrict__ w1,   // [544,64]
                 const float* __restrict__ b1,   // [64]
                 unsigned short* __restrict__ Wt, // [96,512] bf16
                 float* __restrict__ bc)          // [96]
{
    int idx = blockIdx.x * 256 + threadIdx.x;     // 0 .. 96*512-1
    if (idx < NC * DM) {
        int n = idx >> 9, k = idx & 511;
        float v;
        if (n < 32) {
            v = wf[k * 32 + n];
        } else {
            int c = n - 32;
            v = w1[k * 64 + c];
            for (int f = 0; f < 32; ++f)
                v = fmaf(wf[k * 32 + f], w1[(512 + f) * 64 + c], v);
        }
        Wt[idx] = f2bf(v);
    }
    if (idx < NC) {
        float v;
        if (idx < 32) {
            v = bfb[idx];
        } else {
            int c = idx - 32;
            v = b1[c];
            for (int f = 0; f < 32; ++f)
                v = fmaf(bfb[f], w1[(512 + f) * 64 + c], v);
        }
        bc[idx] = v;
    }
}

// ---- kernel 2: split-K MFMA GEMM, M=64/block, N=96, K=512 ----------------
// 512 threads = 8 waves; wave = (kh<<2)|mw. Wave (mw,kh): tokens
// [tok0+16mw, +16), K-half [kh*256, +256) in registers; 6 N-tiles.
__global__ __launch_bounds__(512, 4)
void fused_gemm_kernel(const float* __restrict__ hidden,        // [NTOK,512]
                       const unsigned short* __restrict__ Wt,   // [96,512] bf16
                       const float* __restrict__ bc,            // [96]
                       const float* __restrict__ w2,            // [64]
                       const float* __restrict__ b2,            // [1]
                       float* __restrict__ out_delta,           // [NTOK]
                       float* __restrict__ out_fiber)           // [NTOK,32]
{
    __shared__ __attribute__((aligned(16))) unsigned short b_lds[192 * LROW]; // 52224 B

    const int tid  = threadIdx.x;
    const int wave = tid >> 6;
    const int lane = tid & 63;
    const int quad = lane >> 4;
    const int l15  = lane & 15;
    const int mw   = wave & 3;
    const int kh   = wave >> 2;
    const int tok0 = blockIdx.x * TB;

    // ---- A: my row's K-half into 8 bf16 fragments (frag j: k = j*32+quad*8) ----
    const float* aptr = hidden + (size_t)(tok0 + mw * 16 + l15) * DM + kh * 256 + quad * 8;
    bf16x8 afrag[8];
#pragma unroll
    for (int g = 0; g < 2; ++g) {                 // 2 groups: cap live raw regs at 8 float4
        float4 raw[8];
#pragma unroll
        for (int i = 0; i < 8; ++i)               // i = j'*2 + part
            raw[i] = *(const float4*)(aptr + (g * 4 + (i >> 1)) * 32 + (i & 1) * 4);
#pragma unroll
        for (int j = 0; j < 4; ++j) {
            float4 lo = raw[j * 2], hi = raw[j * 2 + 1];
            bf16x8 f;
            f[0] = (short)f2bf(lo.x); f[1] = (short)f2bf(lo.y);
            f[2] = (short)f2bf(lo.z); f[3] = (short)f2bf(lo.w);
            f[4] = (short)f2bf(hi.x); f[5] = (short)f2bf(hi.y);
            f[6] = (short)f2bf(hi.z); f[7] = (short)f2bf(hi.w);
            afrag[g * 4 + j] = f;
        }
    }

    f32x4 acc[6];
#pragma unroll
    for (int t = 0; t < 6; ++t) acc[t] = (f32x4){0.f, 0.f, 0.f, 0.f};

    for (int s = 0; s < 2; ++s) {                 // 2 steps of 128 k per half
        // stage B: rows 0-95 = half 0 chunk, rows 96-191 = half 1 chunk
#pragma unroll
        for (int it = 0; it < 6; ++it) {
            int v   = it * 512 + tid;             // 3072 x 16B
            int r   = v >> 4;
            int c8  = v & 15;
            int khr = (r >= 96) ? 1 : 0;
            int n   = r - khr * 96;
            *(bf16x8*)&b_lds[r * LROW + c8 * 8] =
                *(const bf16x8*)(Wt + n * DM + khr * 256 + s * 128 + c8 * 8);
        }
        __syncthreads();

#pragma unroll
        for (int ks = 0; ks < 4; ++ks) {
            bf16x8 af = afrag[s * 4 + ks];
#pragma unroll
            for (int t = 0; t < 6; ++t) {
                bf16x8 bv = *(const bf16x8*)&b_lds[(kh * 96 + t * 16 + l15) * LROW + ks * 32 + quad * 8];
                acc[t] = __builtin_amdgcn_mfma_f32_16x16x32_bf16(af, bv, acc[t], 0, 0, 0);
            }
        }
        __syncthreads();
    }

    // ---- cross-half reduction through LDS (reuse b_lds) ----
    f32x4* red = (f32x4*)b_lds;                   // 4*6*64 f32x4 = 24576 B
    if (kh == 1) {
#pragma unroll
        for (int t = 0; t < 6; ++t)
            red[(mw * 6 + t) * 64 + lane] = acc[t];
    }
    __syncthreads();

    if (kh == 0) {
#pragma unroll
        for (int t = 0; t < 6; ++t)
            acc[t] = acc[t] + red[(mw * 6 + t) * 64 + lane];

        // ---- epilogue: C/D layout col=lane&15, row=quad*4+reg ----
        const int mbase = tok0 + mw * 16 + quad * 4;

#pragma unroll
        for (int t = 0; t < 2; ++t) {             // fiber tiles
            int col = t * 16 + l15;
            float bias = bc[col];
#pragma unroll
            for (int r = 0; r < 4; ++r)
                out_fiber[(size_t)(mbase + r) * 32 + col] = acc[t][r] + bias;
        }

        float p0 = 0.f, p1 = 0.f, p2 = 0.f, p3 = 0.f;
#pragma unroll
        for (int t = 2; t < 6; ++t) {             // control tiles: gelu * w2
            int c = (t - 2) * 16 + l15;
            float bias = bc[32 + c];
            float w2v  = w2[c];
            float x, g;
            x = acc[t][0] + bias; g = 0.5f * x * (1.f + erff(x * 0.70710678118f)); p0 = fmaf(g, w2v, p0);
            x = acc[t][1] + bias; g = 0.5f * x * (1.f + erff(x * 0.70710678118f)); p1 = fmaf(g, w2v, p1);
            x = acc[t][2] + bias; g = 0.5f * x * (1.f + erff(x * 0.70710678118f)); p2 = fmaf(g, w2v, p2);
            x = acc[t][3] + bias; g = 0.5f * x * (1.f + erff(x * 0.70710678118f)); p3 = fmaf(g, w2v, p3);
        }
#pragma unroll
        for (int m = 1; m <= 8; m <<= 1) {        // reduce 16 lanes of this quad
            p0 += __shfl_xor(p0, m);
            p1 += __shfl_xor(p1, m);
            p2 += __shfl_xor(p2, m);
            p3 += __shfl_xor(p3, m);
        }
        if (l15 < 4) {
            float pv = (l15 == 0) ? p0 : (l15 == 1) ? p1 : (l15 == 2) ? p2 : p3;
            float sft = pv + b2[0];
            float d = (sft > 0.f) ? sft + log1pf(expf(-sft)) : log1pf(expf(sft));
            d = fminf(fmaxf(d, 0.f), 1.f);
            out_delta[mbase + l15] = d;
        }
    }
}

// ---- kernel 3: exact associative EMA scan + gate; 1 block per batch row ---
__global__ __launch_bounds__(512)
void scan_kernel(const float* __restrict__ delta,   // [8,4096]
                 const float* __restrict__ lam,     // scalar
                 float* __restrict__ out_gate,      // [NTOK]
                 float* __restrict__ out_field)     // [NTOK]
{
    __shared__ float sA[8], sB[8];
    const int b    = blockIdx.x;
    const int tid  = threadIdx.x;
    const int lane = tid & 63;
    const int wv   = tid >> 6;

    const float* dp = delta + (size_t)b * SEQ + tid * 8;
    float4 d0 = *(const float4*)dp;
    float4 d1 = *(const float4*)(dp + 4);
    float d[8] = {d0.x, d0.y, d0.z, d0.w, d1.x, d1.y, d1.z, d1.w};

    float x = 0.f;
#pragma unroll
    for (int j = 0; j < 8; ++j) x = fmaf(0.9f, x, 0.1f * d[j]);
    float A = 0.430467196f;   // 0.9^8
    float B = x;

#pragma unroll
    for (int m = 1; m <= 32; m <<= 1) {
        float Au = __shfl_up(A, m);
        float Bu = __shfl_up(B, m);
        if (lane >= m) { B = fmaf(A, Bu, B); A *= Au; }
    }
    if (lane == 63) { sA[wv] = A; sB[wv] = B; }
    __syncthreads();

    float cB = 0.f;
    for (int i = 0; i < wv; ++i) cB = fmaf(sA[i], cB, sB[i]);

    float Ap = __shfl_up(A, 1);
    float Bp = __shfl_up(B, 1);
    float f0 = (lane == 0) ? cB : fmaf(Ap, cB, Bp);

    const float lamv = lam[0];
    float xx = f0;
    float4 of0, of1, og0, og1;
#pragma unroll
    for (int j = 0; j < 8; ++j) {
        xx = fmaf(0.9f, xx, 0.1f * d[j]);
        float field = fminf(fmaxf(xx, 0.f), 10.f);
        float gate  = 1.f / (1.f + expf(lamv * field));
        if (j < 4) { (&of0.x)[j] = field; (&og0.x)[j] = gate; }
        else       { (&of1.x)[j - 4] = field; (&og1.x)[j - 4] = gate; }
    }
    size_t o = (size_t)b * SEQ + tid * 8;
    *(float4*)(out_field + o)     = of0;
    *(float4*)(out_field + o + 4) = of1;
    *(float4*)(out_gate  + o)     = og0;
    *(float4*)(out_gate  + o + 4) = og1;
}

// ---- launcher ----
extern "C" void kernel_launch(void* const* d_in, const int* in_sizes, int n_in,
                              void* d_out, int out_size, void* d_ws, size_t ws_size,
                              hipStream_t stream)
{
    const float* hidden = (const float*)d_in[0];
    const float* wf     = (const float*)d_in[1];
    const float* bfb    = (const float*)d_in[2];
    const float* w1     = (const float*)d_in[3];
    const float* b1     = (const float*)d_in[4];
    const float* w2     = (const float*)d_in[5];
    const float* b2     = (const float*)d_in[6];
    const float* lam    = (const float*)d_in[7];
    float* out = (float*)d_out;
    // out layout: gate[32768] | field[32768] | delta[32768] | fiber[32768*32]
    float* out_gate  = out;
    float* out_field = out + NTOK;
    float* out_delta = out + 2 * NTOK;
    float* out_fiber = out + 3 * NTOK;

    unsigned short* Wt = (unsigned short*)d_ws;                 // 96*512*2 B
    float* bc          = (float*)((char*)d_ws + NC * DM * 2);   // 384 B

    hipLaunchKernelGGL(prep_kernel, dim3((NC * DM + 255) / 256), dim3(256), 0, stream,
                       wf, bfb, w1, b1, Wt, bc);
    hipLaunchKernelGGL(fused_gemm_kernel, dim3(NTOK / TB), dim3(512), 0, stream,
                       hidden, Wt, bc, w2, b2, out_delta, out_fiber);
    hipLaunchKernelGGL(scan_kernel, dim3(8), dim3(512), 0, stream,
                       out_delta, lam, out_gate, out_field);
}